// Round 1
// baseline (357.610 us; speedup 1.0000x reference)
//
#include <hip/hip_runtime.h>
#include <hip/hip_bf16.h>

#define D_MODEL 1024
#define T_SEQ   2048
#define BATCH   2
#define NHEADS  16
#define HDIM    64

typedef __bf16 bf16_t;
typedef bf16_t bf16x8 __attribute__((ext_vector_type(8)));
typedef float  f32x4  __attribute__((ext_vector_type(4)));

__device__ __forceinline__ unsigned short f2bf(float f) {
    union { float f; unsigned u; } v; v.f = f;
    unsigned u = v.u;
    u += 0x7FFFu + ((u >> 16) & 1u);   // round-to-nearest-even
    return (unsigned short)(u >> 16);
}

// ---------------- f32 -> bf16 convert (vectorized) ----------------
__global__ void cvt_f32_bf16(const float* __restrict__ src,
                             unsigned short* __restrict__ dst, int n4) {
    int i = blockIdx.x * blockDim.x + threadIdx.x;
    if (i < n4) {
        float4 v = reinterpret_cast<const float4*>(src)[i];
        ushort4 o;
        o.x = f2bf(v.x); o.y = f2bf(v.y); o.z = f2bf(v.z); o.w = f2bf(v.w);
        reinterpret_cast<ushort4*>(dst)[i] = o;
    }
}

// ---------------- 64x64-tile bf16 GEMM, C = A @ B + bias ----------------
// A: [M][K] bf16 row-major. B: [K][N] bf16 row-major (transposed into LDS).
// MODE 0: scatter into qkv [3][B][H][T][Hd] bf16.  MODE 1: f32 out [M][N].
template<int MODE>
__global__ __launch_bounds__(256) void gemm64(
    const unsigned short* __restrict__ A,
    const unsigned short* __restrict__ Bm,
    const float* __restrict__ bias,
    unsigned short* __restrict__ qkv,   // MODE 0
    float* __restrict__ outf,           // MODE 1
    int M, int N, int K)
{
    __shared__ unsigned short As[64][32];   // [m][k]
    __shared__ unsigned short Bs[64][32];   // [n][k]  (B^T tile)
    const int tid  = threadIdx.x;
    const int wv   = tid >> 6;
    const int lane = tid & 63;
    const int m0 = blockIdx.y * 64;
    const int n0 = blockIdx.x * 64;

    f32x4 acc[4] = {};

    for (int k0 = 0; k0 < K; k0 += 32) {
        // stage A tile: 64x32, 256 thr x 8 elems
        {
            int row = tid >> 2, cb = (tid & 3) * 8;
            *reinterpret_cast<uint4*>(&As[row][cb]) =
                *reinterpret_cast<const uint4*>(A + (size_t)(m0 + row) * K + k0 + cb);
        }
        // stage B tile transposed: 32x64 -> Bs[n][k]
        {
            int brow = tid >> 3, bcb = (tid & 7) * 8;
            unsigned short tmp[8];
            *reinterpret_cast<uint4*>(tmp) =
                *reinterpret_cast<const uint4*>(Bm + (size_t)(k0 + brow) * N + n0 + bcb);
            #pragma unroll
            for (int i = 0; i < 8; ++i) Bs[bcb + i][brow] = tmp[i];
        }
        __syncthreads();

        const bf16x8 av = *reinterpret_cast<const bf16x8*>(&As[16 * wv + (lane & 15)][(lane >> 4) * 8]);
        #pragma unroll
        for (int jc = 0; jc < 4; ++jc) {
            const bf16x8 bv = *reinterpret_cast<const bf16x8*>(&Bs[16 * jc + (lane & 15)][(lane >> 4) * 8]);
            acc[jc] = __builtin_amdgcn_mfma_f32_16x16x32_bf16(av, bv, acc[jc], 0, 0, 0);
        }
        __syncthreads();
    }

    // epilogue: D row = (lane>>4)*4 + jr, col = lane&15 (within each 16x16)
    const int rbase = m0 + 16 * wv + ((lane >> 4) << 2);
    const int cb0   = n0 + (lane & 15);
    #pragma unroll
    for (int jc = 0; jc < 4; ++jc) {
        const int c = cb0 + 16 * jc;
        const float bc = bias[c];
        #pragma unroll
        for (int jr = 0; jr < 4; ++jr) {
            const int r = rbase + jr;
            const float val = acc[jc][jr] + bc;
            if (MODE == 0) {
                const int which = c >> 10;
                const int rem   = c & 1023;
                const int h     = rem >> 6;
                const int hd    = rem & 63;
                const int b     = r >> 11;
                const int t     = r & 2047;
                qkv[(size_t)which * (BATCH * NHEADS * T_SEQ * HDIM)
                    + ((((size_t)b * NHEADS + h) * T_SEQ + t) << 6) + hd] = f2bf(val);
            } else {
                outf[(size_t)r * N + c] = val;
            }
        }
    }
}

// ---------------- flash attention: one block per (b, h, 64-row Q tile) ----------------
__global__ __launch_bounds__(256) void attn64(
    const unsigned short* __restrict__ qb,
    const unsigned short* __restrict__ kb,
    const unsigned short* __restrict__ vb,
    unsigned short* __restrict__ ctx)   // [B][T][D] bf16
{
    __shared__ unsigned short Ks[64][64];   // [krow][hd]
    __shared__ unsigned short Vt[64][64];   // [hd][krow]
    __shared__ unsigned short Ps[64][64];   // [qrow][krow]; also Q staging

    const int tid  = threadIdx.x;
    const int wv   = tid >> 6;
    const int lane = tid & 63;
    const int qt = blockIdx.x, h = blockIdx.y, b = blockIdx.z;

    const size_t base = ((size_t)(b * NHEADS + h)) * T_SEQ * HDIM;
    const unsigned short* Q  = qb + base + (size_t)qt * 64 * HDIM;
    const unsigned short* Kp = kb + base;
    const unsigned short* Vp = vb + base;

    const int srow = tid >> 2;          // 0..63
    const int scb  = (tid & 3) * 16;    // 0,16,32,48

    // stage Q (via Ps), grab fragments
    *reinterpret_cast<uint4*>(&Ps[srow][scb]) =
        *reinterpret_cast<const uint4*>(Q + (size_t)srow * HDIM + scb);
    *reinterpret_cast<uint4*>(&Ps[srow][scb + 8]) =
        *reinterpret_cast<const uint4*>(Q + (size_t)srow * HDIM + scb + 8);
    __syncthreads();
    const bf16x8 qf0 = *reinterpret_cast<const bf16x8*>(&Ps[16 * wv + (lane & 15)][(lane >> 4) * 8]);
    const bf16x8 qf1 = *reinterpret_cast<const bf16x8*>(&Ps[16 * wv + (lane & 15)][32 + (lane >> 4) * 8]);
    __syncthreads();

    float m[4], l[4];
    f32x4 o[4] = {};
    #pragma unroll
    for (int j = 0; j < 4; ++j) { m[j] = -1e30f; l[j] = 0.f; }

    for (int kt = 0; kt < T_SEQ / 64; ++kt) {
        // stage K rows + V transposed
        {
            const unsigned short* krow_p = Kp + (size_t)(kt * 64 + srow) * HDIM;
            *reinterpret_cast<uint4*>(&Ks[srow][scb]) =
                *reinterpret_cast<const uint4*>(krow_p + scb);
            *reinterpret_cast<uint4*>(&Ks[srow][scb + 8]) =
                *reinterpret_cast<const uint4*>(krow_p + scb + 8);
            const unsigned short* vrow_p = Vp + (size_t)(kt * 64 + srow) * HDIM;
            unsigned short tv[16];
            *reinterpret_cast<uint4*>(&tv[0]) = *reinterpret_cast<const uint4*>(vrow_p + scb);
            *reinterpret_cast<uint4*>(&tv[8]) = *reinterpret_cast<const uint4*>(vrow_p + scb + 8);
            #pragma unroll
            for (int i = 0; i < 16; ++i) Vt[scb + i][srow] = tv[i];
        }
        __syncthreads();

        // S = Q K^T   (wave covers 16 q-rows x 64 keys)
        f32x4 s[4];
        #pragma unroll
        for (int jc = 0; jc < 4; ++jc) {
            const bf16x8 b0 = *reinterpret_cast<const bf16x8*>(&Ks[16 * jc + (lane & 15)][(lane >> 4) * 8]);
            const bf16x8 b1 = *reinterpret_cast<const bf16x8*>(&Ks[16 * jc + (lane & 15)][32 + (lane >> 4) * 8]);
            f32x4 z = {};
            z     = __builtin_amdgcn_mfma_f32_16x16x32_bf16(qf0, b0, z, 0, 0, 0);
            s[jc] = __builtin_amdgcn_mfma_f32_16x16x32_bf16(qf1, b1, z, 0, 0, 0);
        }

        // online softmax (rows live across 16-lane groups, 4 regs each)
        float p[4][4];
        #pragma unroll
        for (int jr = 0; jr < 4; ++jr) {
            float mx = s[0][jr];
            #pragma unroll
            for (int jc = 1; jc < 4; ++jc) mx = fmaxf(mx, s[jc][jr]);
            mx *= 0.125f;
            mx = fmaxf(mx, __shfl_xor(mx, 1));
            mx = fmaxf(mx, __shfl_xor(mx, 2));
            mx = fmaxf(mx, __shfl_xor(mx, 4));
            mx = fmaxf(mx, __shfl_xor(mx, 8));
            const float mn = fmaxf(m[jr], mx);
            const float sc = __expf(m[jr] - mn);
            float rs = 0.f;
            #pragma unroll
            for (int jc = 0; jc < 4; ++jc) {
                const float pv = __expf(s[jc][jr] * 0.125f - mn);
                p[jc][jr] = pv;
                rs += pv;
            }
            rs += __shfl_xor(rs, 1);
            rs += __shfl_xor(rs, 2);
            rs += __shfl_xor(rs, 4);
            rs += __shfl_xor(rs, 8);
            l[jr] = l[jr] * sc + rs;
            m[jr] = mn;
            #pragma unroll
            for (int n = 0; n < 4; ++n) o[n][jr] *= sc;
        }

        // write P tile (bf16)
        #pragma unroll
        for (int jc = 0; jc < 4; ++jc)
            #pragma unroll
            for (int jr = 0; jr < 4; ++jr)
                Ps[16 * wv + ((lane >> 4) << 2) + jr][16 * jc + (lane & 15)] = f2bf(p[jc][jr]);
        __syncthreads();

        // O += P V
        #pragma unroll
        for (int n = 0; n < 4; ++n) {
            #pragma unroll
            for (int kk = 0; kk < 2; ++kk) {
                const bf16x8 pa = *reinterpret_cast<const bf16x8*>(&Ps[16 * wv + (lane & 15)][32 * kk + (lane >> 4) * 8]);
                const bf16x8 vv = *reinterpret_cast<const bf16x8*>(&Vt[16 * n + (lane & 15)][32 * kk + (lane >> 4) * 8]);
                o[n] = __builtin_amdgcn_mfma_f32_16x16x32_bf16(pa, vv, o[n], 0, 0, 0);
            }
        }
        __syncthreads();
    }

    // normalize + write context [B][T][D]
    #pragma unroll
    for (int jr = 0; jr < 4; ++jr) {
        const float inv = 1.0f / l[jr];
        const int t = qt * 64 + 16 * wv + ((lane >> 4) << 2) + jr;
        #pragma unroll
        for (int n = 0; n < 4; ++n) {
            const int c = h * HDIM + 16 * n + (lane & 15);
            ctx[((size_t)b * T_SEQ + t) * D_MODEL + c] = f2bf(o[n][jr] * inv);
        }
    }
}

extern "C" void kernel_launch(void* const* d_in, const int* in_sizes, int n_in,
                              void* d_out, int out_size, void* d_ws, size_t ws_size,
                              hipStream_t stream) {
    const float* x    = (const float*)d_in[0];
    const float* Wqkv = (const float*)d_in[1];
    const float* bqkv = (const float*)d_in[2];
    const float* Wout = (const float*)d_in[3];
    const float* bout = (const float*)d_in[4];
    float* out = (float*)d_out;

    char* ws = (char*)d_ws;
    unsigned short* xb    = (unsigned short*)(ws);                 // 8 MB
    unsigned short* wqkvb = (unsigned short*)(ws + 8388608);       // 6 MB
    unsigned short* woutb = (unsigned short*)(ws + 14680064);      // 2 MB
    unsigned short* qkv   = (unsigned short*)(ws + 16777216);      // 24 MB (q,k,v)
    unsigned short* ctx   = (unsigned short*)(ws + 41943040);      // 8 MB

    int n4;
    n4 = (BATCH * T_SEQ * D_MODEL) / 4;
    cvt_f32_bf16<<<(n4 + 255) / 256, 256, 0, stream>>>(x, xb, n4);
    n4 = (D_MODEL * 3 * D_MODEL) / 4;
    cvt_f32_bf16<<<(n4 + 255) / 256, 256, 0, stream>>>(Wqkv, wqkvb, n4);
    n4 = (D_MODEL * D_MODEL) / 4;
    cvt_f32_bf16<<<(n4 + 255) / 256, 256, 0, stream>>>(Wout, woutb, n4);

    dim3 g1(3 * D_MODEL / 64, (BATCH * T_SEQ) / 64);
    gemm64<0><<<g1, 256, 0, stream>>>(xb, wqkvb, bqkv, qkv, nullptr,
                                      BATCH * T_SEQ, 3 * D_MODEL, D_MODEL);

    dim3 g2(T_SEQ / 64, NHEADS, BATCH);
    attn64<<<g2, 256, 0, stream>>>(qkv,
                                   qkv + (size_t)BATCH * NHEADS * T_SEQ * HDIM,
                                   qkv + (size_t)2 * BATCH * NHEADS * T_SEQ * HDIM,
                                   ctx);

    dim3 g3(D_MODEL / 64, (BATCH * T_SEQ) / 64);
    gemm64<1><<<g3, 256, 0, stream>>>(ctx, woutb, bout, nullptr, out,
                                      BATCH * T_SEQ, D_MODEL, D_MODEL);
}

// Round 2
// 219.143 us; speedup vs baseline: 1.6319x; 1.6319x over previous
//
#include <hip/hip_runtime.h>
#include <hip/hip_bf16.h>

#define D_MODEL 1024
#define T_SEQ   2048
#define BATCH   2
#define NHEADS  16
#define HDIM    64
#define QKVSZ   (BATCH * NHEADS * T_SEQ * HDIM)   // 4,194,304 elems per matrix

typedef __bf16 bf16_t;
typedef bf16_t bf16x8 __attribute__((ext_vector_type(8)));
typedef float  f32x4  __attribute__((ext_vector_type(4)));

__device__ __forceinline__ unsigned short f2bf(float f) {
    union { float f; unsigned u; } v; v.f = f;
    unsigned u = v.u;
    u += 0x7FFFu + ((u >> 16) & 1u);   // round-to-nearest-even
    return (unsigned short)(u >> 16);
}

// async global->LDS, 16B per lane; LDS dest must be wave-uniform base (HW adds lane*16)
__device__ __forceinline__ void gload16(const unsigned short* g, unsigned short* l) {
    __builtin_amdgcn_global_load_lds(
        (const __attribute__((address_space(1))) void*)g,
        (__attribute__((address_space(3))) void*)l,
        16, 0, 0);
}

// ---------------- f32 -> bf16 convert (vectorized) ----------------
__global__ void cvt_f32_bf16(const float* __restrict__ src,
                             unsigned short* __restrict__ dst, int n4) {
    int i = blockIdx.x * blockDim.x + threadIdx.x;
    if (i < n4) {
        float4 v = reinterpret_cast<const float4*>(src)[i];
        ushort4 o;
        o.x = f2bf(v.x); o.y = f2bf(v.y); o.z = f2bf(v.z); o.w = f2bf(v.w);
        reinterpret_cast<ushort4*>(dst)[i] = o;
    }
}

// ---------------- f32 [K][N] -> bf16 [N][K] transpose-convert ----------------
__global__ __launch_bounds__(256) void cvt_transpose(
    const float* __restrict__ src, unsigned short* __restrict__ dst, int K, int N)
{
    __shared__ unsigned short Ls[64][72];   // +8 pad keeps 16B alignment (144B rows)
    const int n0 = blockIdx.x * 64, k0 = blockIdx.y * 64;
    const int tid = threadIdx.x;
    #pragma unroll
    for (int it = 0; it < 4; ++it) {
        const int r = it * 16 + (tid >> 4);     // k-row
        const int c = (tid & 15) * 4;           // n-col
        float4 v = *reinterpret_cast<const float4*>(src + (size_t)(k0 + r) * N + n0 + c);
        Ls[c + 0][r] = f2bf(v.x); Ls[c + 1][r] = f2bf(v.y);
        Ls[c + 2][r] = f2bf(v.z); Ls[c + 3][r] = f2bf(v.w);
    }
    __syncthreads();
    #pragma unroll
    for (int it = 0; it < 2; ++it) {
        const int rn = it * 32 + (tid >> 3);
        const int ck = (tid & 7) * 8;
        *reinterpret_cast<uint4*>(dst + (size_t)(n0 + rn) * K + k0 + ck) =
            *reinterpret_cast<const uint4*>(&Ls[rn][ck]);
    }
}

// ---------------- 128x128-tile bf16 GEMM (m97 structure) ----------------
// A: [M][K] bf16. BT: [N][K] bf16 (pre-transposed). LDS swizzle: slot ^= (row>>1)&3.
// MODE 0: scatter into Q,K [b][h][t][hd] + V^T [b][h][hd][t].  MODE 1: f32 out + bias.
template<int MODE>
__global__ __launch_bounds__(256) void gemm128(
    const unsigned short* __restrict__ A,
    const unsigned short* __restrict__ BT,
    const float* __restrict__ bias,
    unsigned short* __restrict__ qkv,
    float* __restrict__ outf,
    int M, int N, int K)
{
    __shared__ unsigned short As[128 * 32];
    __shared__ unsigned short Bs[128 * 32];
    const int tid = threadIdx.x, wv = tid >> 6, lane = tid & 63;
    const int wr = wv >> 1, wc = wv & 1;
    const int m0 = blockIdx.y * 128, n0 = blockIdx.x * 128;

    f32x4 acc[4][4] = {};

    for (int k0 = 0; k0 < K; k0 += 32) {
        #pragma unroll
        for (int i = 0; i < 2; ++i) {
            const int rbase = 32 * wv + 16 * i;
            const int row = rbase + (lane >> 2);
            const int kc  = (lane & 3) ^ ((row >> 1) & 3);   // pre-swizzled source
            gload16(A  + (size_t)(m0 + row) * K + k0 + kc * 8, &As[rbase * 32]);
            gload16(BT + (size_t)(n0 + row) * K + k0 + kc * 8, &Bs[rbase * 32]);
        }
        __syncthreads();

        bf16x8 af[4], bfr[4];
        #pragma unroll
        for (int m = 0; m < 4; ++m) {
            const int row = 64 * wr + 16 * m + (lane & 15);
            const int s   = (lane >> 4) ^ ((row >> 1) & 3);
            af[m] = *reinterpret_cast<const bf16x8*>(&As[row * 32 + s * 8]);
        }
        #pragma unroll
        for (int n = 0; n < 4; ++n) {
            const int row = 64 * wc + 16 * n + (lane & 15);
            const int s   = (lane >> 4) ^ ((row >> 1) & 3);
            bfr[n] = *reinterpret_cast<const bf16x8*>(&Bs[row * 32 + s * 8]);
        }
        #pragma unroll
        for (int m = 0; m < 4; ++m)
            #pragma unroll
            for (int n = 0; n < 4; ++n)
                acc[m][n] = __builtin_amdgcn_mfma_f32_16x16x32_bf16(af[m], bfr[n], acc[m][n], 0, 0, 0);
        __syncthreads();
    }

    // epilogue: D col = lane&15, row = (lane>>4)*4 + jr within each 16x16
    const int rb = m0 + 64 * wr + ((lane >> 4) << 2);
    const int cb = n0 + 64 * wc + (lane & 15);
    #pragma unroll
    for (int n = 0; n < 4; ++n) {
        const int c = cb + 16 * n;
        const float bc = bias[c];
        #pragma unroll
        for (int m = 0; m < 4; ++m) {
            #pragma unroll
            for (int jr = 0; jr < 4; ++jr) {
                const int r = rb + 16 * m + jr;
                const float val = acc[m][n][jr] + bc;
                if (MODE == 0) {
                    const int which = c >> 10;
                    const int rem = c & 1023;
                    const int h = rem >> 6, hd = rem & 63;
                    const int b = r >> 11, t = r & 2047;
                    if (which < 2)
                        qkv[(size_t)which * QKVSZ + ((((size_t)b * NHEADS + h) * T_SEQ + t) << 6) + hd] = f2bf(val);
                    else
                        qkv[(size_t)2 * QKVSZ + ((((size_t)b * NHEADS + h) * HDIM + hd) << 11) + t] = f2bf(val);
                } else {
                    outf[(size_t)r * N + c] = val;
                }
            }
        }
    }
}

// ---------------- flash attention: block = (b, h, 64-row Q tile) ----------------
// K: [b][h][t][hd].  V^T: [b][h][hd][t].  All LDS tiles [64][64] with slot ^= row&7.
__global__ __launch_bounds__(256) void attn64(
    const unsigned short* __restrict__ qb,
    const unsigned short* __restrict__ kb,
    const unsigned short* __restrict__ vtb,
    unsigned short* __restrict__ ctx)   // [B][T][D] bf16
{
    __shared__ unsigned short Ks[64 * 64];
    __shared__ unsigned short Vt[64 * 64];   // [hd][key]
    __shared__ unsigned short Ps[64 * 64];   // [qrow][key]

    const int tid = threadIdx.x, wv = tid >> 6, lane = tid & 63;
    const int qt = blockIdx.x, h = blockIdx.y, b = blockIdx.z;

    const size_t base = ((size_t)(b * NHEADS + h)) * T_SEQ * HDIM;
    const unsigned short* Q   = qb  + base + (size_t)qt * 64 * HDIM;
    const unsigned short* Kp  = kb  + base;
    const unsigned short* Vtp = vtb + base;   // [hd][t], row stride T_SEQ

    // ---- stage Q (into Ks buffer), pull fragments ----
    #pragma unroll
    for (int i = 0; i < 2; ++i) {
        const int rbase = 16 * wv + 8 * i;
        const int row = rbase + (lane >> 3);
        const int kc  = (lane & 7) ^ (row & 7);
        gload16(Q + (size_t)row * HDIM + kc * 8, &Ks[rbase * 64]);
    }
    __syncthreads();
    const int qrow = 16 * wv + (lane & 15);
    const bf16x8 qf0 = *reinterpret_cast<const bf16x8*>(&Ks[qrow * 64 + (((lane >> 4)    ) ^ (qrow & 7)) * 8]);
    const bf16x8 qf1 = *reinterpret_cast<const bf16x8*>(&Ks[qrow * 64 + (((lane >> 4) + 4) ^ (qrow & 7)) * 8]);
    __syncthreads();

    float m[4], l[4];
    f32x4 o[4] = {};
    #pragma unroll
    for (int j = 0; j < 4; ++j) { m[j] = -1e30f; l[j] = 0.f; }

    for (int kt = 0; kt < T_SEQ / 64; ++kt) {
        // ---- stage K rows + V^T rows (async, pre-swizzled source) ----
        #pragma unroll
        for (int i = 0; i < 2; ++i) {
            const int rbase = 16 * wv + 8 * i;
            const int row = rbase + (lane >> 3);
            const int kc  = (lane & 7) ^ (row & 7);
            gload16(Kp  + (size_t)(kt * 64 + row) * HDIM + kc * 8, &Ks[rbase * 64]);
            gload16(Vtp + (size_t)row * T_SEQ + kt * 64 + kc * 8,  &Vt[rbase * 64]);
        }
        __syncthreads();

        // ---- S = Q K^T ----
        f32x4 s[4];
        #pragma unroll
        for (int jc = 0; jc < 4; ++jc) {
            const int krow = 16 * jc + (lane & 15);
            const bf16x8 b0 = *reinterpret_cast<const bf16x8*>(&Ks[krow * 64 + (((lane >> 4)    ) ^ (krow & 7)) * 8]);
            const bf16x8 b1 = *reinterpret_cast<const bf16x8*>(&Ks[krow * 64 + (((lane >> 4) + 4) ^ (krow & 7)) * 8]);
            f32x4 z = {};
            z     = __builtin_amdgcn_mfma_f32_16x16x32_bf16(qf0, b0, z, 0, 0, 0);
            s[jc] = __builtin_amdgcn_mfma_f32_16x16x32_bf16(qf1, b1, z, 0, 0, 0);
        }

        // ---- online softmax (rows in 16-lane groups, 4 regs each) ----
        float p[4][4];
        #pragma unroll
        for (int jr = 0; jr < 4; ++jr) {
            float mx = s[0][jr];
            #pragma unroll
            for (int jc = 1; jc < 4; ++jc) mx = fmaxf(mx, s[jc][jr]);
            mx *= 0.125f;
            mx = fmaxf(mx, __shfl_xor(mx, 1));
            mx = fmaxf(mx, __shfl_xor(mx, 2));
            mx = fmaxf(mx, __shfl_xor(mx, 4));
            mx = fmaxf(mx, __shfl_xor(mx, 8));
            const float mn = fmaxf(m[jr], mx);
            const float sc = __expf(m[jr] - mn);
            float rs = 0.f;
            #pragma unroll
            for (int jc = 0; jc < 4; ++jc) {
                const float pv = __expf(s[jc][jr] * 0.125f - mn);
                p[jc][jr] = pv;
                rs += pv;
            }
            rs += __shfl_xor(rs, 1);
            rs += __shfl_xor(rs, 2);
            rs += __shfl_xor(rs, 4);
            rs += __shfl_xor(rs, 8);
            l[jr] = l[jr] * sc + rs;
            m[jr] = mn;
            #pragma unroll
            for (int n = 0; n < 4; ++n) o[n][jr] *= sc;
        }

        // ---- write P tile (bf16, swizzled) ----
        #pragma unroll
        for (int jc = 0; jc < 4; ++jc) {
            #pragma unroll
            for (int jr = 0; jr < 4; ++jr) {
                const int prow = 16 * wv + ((lane >> 4) << 2) + jr;
                const int key  = 16 * jc + (lane & 15);
                Ps[prow * 64 + (((key >> 3) ^ (prow & 7)) << 3) + (key & 7)] = f2bf(p[jc][jr]);
            }
        }
        __syncthreads();

        // ---- O += P V ----
        #pragma unroll
        for (int n = 0; n < 4; ++n) {
            #pragma unroll
            for (int kk = 0; kk < 2; ++kk) {
                const int prow = 16 * wv + (lane & 15);
                const int vrow = 16 * n  + (lane & 15);
                const int kc   = 4 * kk + (lane >> 4);
                const bf16x8 pa = *reinterpret_cast<const bf16x8*>(&Ps[prow * 64 + (kc ^ (prow & 7)) * 8]);
                const bf16x8 vvv = *reinterpret_cast<const bf16x8*>(&Vt[vrow * 64 + (kc ^ (vrow & 7)) * 8]);
                o[n] = __builtin_amdgcn_mfma_f32_16x16x32_bf16(pa, vvv, o[n], 0, 0, 0);
            }
        }
        __syncthreads();
    }

    // ---- normalize + write context [B][T][D] ----
    #pragma unroll
    for (int jr = 0; jr < 4; ++jr) {
        const float inv = 1.0f / l[jr];
        const int t = qt * 64 + 16 * wv + ((lane >> 4) << 2) + jr;
        #pragma unroll
        for (int n = 0; n < 4; ++n) {
            const int c = h * HDIM + 16 * n + (lane & 15);
            ctx[((size_t)b * T_SEQ + t) * D_MODEL + c] = f2bf(o[n][jr] * inv);
        }
    }
}

extern "C" void kernel_launch(void* const* d_in, const int* in_sizes, int n_in,
                              void* d_out, int out_size, void* d_ws, size_t ws_size,
                              hipStream_t stream) {
    const float* x    = (const float*)d_in[0];
    const float* Wqkv = (const float*)d_in[1];
    const float* bqkv = (const float*)d_in[2];
    const float* Wout = (const float*)d_in[3];
    const float* bout = (const float*)d_in[4];
    float* out = (float*)d_out;

    char* ws = (char*)d_ws;
    unsigned short* xb    = (unsigned short*)(ws);                 // 8 MB
    unsigned short* wqkvT = (unsigned short*)(ws + 8388608);       // 6 MB  [3072][1024]
    unsigned short* woutT = (unsigned short*)(ws + 14680064);      // 2 MB  [1024][1024]
    unsigned short* qkv   = (unsigned short*)(ws + 16777216);      // 24 MB (Q, K, V^T)
    unsigned short* ctx   = (unsigned short*)(ws + 41943040);      // 8 MB

    int n4 = (BATCH * T_SEQ * D_MODEL) / 4;
    cvt_f32_bf16<<<(n4 + 255) / 256, 256, 0, stream>>>(x, xb, n4);

    dim3 gt1(3 * D_MODEL / 64, D_MODEL / 64);
    cvt_transpose<<<gt1, 256, 0, stream>>>(Wqkv, wqkvT, D_MODEL, 3 * D_MODEL);
    dim3 gt2(D_MODEL / 64, D_MODEL / 64);
    cvt_transpose<<<gt2, 256, 0, stream>>>(Wout, woutT, D_MODEL, D_MODEL);

    dim3 g1(3 * D_MODEL / 128, (BATCH * T_SEQ) / 128);
    gemm128<0><<<g1, 256, 0, stream>>>(xb, wqkvT, bqkv, qkv, nullptr,
                                       BATCH * T_SEQ, 3 * D_MODEL, D_MODEL);

    dim3 g2(T_SEQ / 64, NHEADS, BATCH);
    attn64<<<g2, 256, 0, stream>>>(qkv,
                                   qkv + (size_t)QKVSZ,
                                   qkv + (size_t)2 * QKVSZ,
                                   ctx);

    dim3 g3(D_MODEL / 128, (BATCH * T_SEQ) / 128);
    gemm128<1><<<g3, 256, 0, stream>>>(ctx, woutT, bout, nullptr, out,
                                       BATCH * T_SEQ, D_MODEL, D_MODEL);
}